// Round 11
// baseline (176.071 us; speedup 1.0000x reference)
//
#include <hip/hip_runtime.h>

// ---- problem constants ----
#define NB 8192      // batch rows
#define NM 1024      // image dim
#define NK 2048      // dictionary size

typedef unsigned short ushort_t;
using bf16x8 = __attribute__((ext_vector_type(8))) short;
using f32x4  = __attribute__((ext_vector_type(4))) float;

// T = 101 provably: accept at t=101 holds for all b/a > 0; flip at t=100
// would need b/a >= ~4e6 but b/a <= tr(W W^T) = 2048 (unit-norm cols).
__device__ __forceinline__ float alpha_const() {
  const double s = 0.1 * (2.0 / 8388608.0);
  return (float)(101.0 * s);
}

__device__ __forceinline__ ushort_t f2bf(float f) {
  union { float f; unsigned u; } v; v.f = f;
  unsigned r = (v.u + 0x7FFFu + ((v.u >> 16) & 1u)) >> 16;  // RNE
  return (ushort_t)r;
}

__device__ __forceinline__ void gload_lds16(const void* g, void* l) {
  __builtin_amdgcn_global_load_lds(
      (const __attribute__((address_space(1))) unsigned int*)g,
      (__attribute__((address_space(3))) unsigned int*)l, 16, 0, 0);
}

// ===== fused prep (1600 blocks):
//   b <  1024 : img -> bf16 (32 KB f32 per block)
//   b <  1536 : W 64x64 tile transpose -> Wt
//   b >= 1536 : Q = bf16(W @ W^T), 128^2 tiles (64 blocks), reg-staged f32->bf16
// Q's per-element K-accumulation order (k0 asc, ks 0/1, 16x16x32 MFMA, manual
// RNE f2bf operands) matches all prior rounds -> Q bitwise identical.
__global__ __launch_bounds__(256)
void prep_k(const float* __restrict__ img, const float* __restrict__ W,
            ushort_t* __restrict__ imgbf, ushort_t* __restrict__ Wt,
            ushort_t* __restrict__ Qbf)
{
  __shared__ __align__(128) char smem[32768];
  const int tid = threadIdx.x;
  const int b = blockIdx.x;

  if (b < 1024) {
    // ---- img -> bf16: 1024 blocks x 8 float4/thread ----
    const int base = b * 2048;
#pragma unroll
    for (int i = 0; i < 8; ++i) {
      const int idx = base + i * 256 + tid;
      const float4 v = ((const float4*)img)[idx];
      ushort4 o;
      o.x = f2bf(v.x); o.y = f2bf(v.y); o.z = f2bf(v.z); o.w = f2bf(v.w);
      ((ushort4*)imgbf)[idx] = o;
    }
  } else if (b < 1536) {
    // ---- W 64x64 tile transpose -> Wt (512 tiles: 16m x 32k) ----
    ushort_t (*tile)[65] = (ushort_t(*)[65])smem;
    const int bW = b - 1024;
    const int m0 = (bW >> 5) * 64, k0 = (bW & 31) * 64;
    const int r = tid >> 2, q = tid & 3;
    ushort_t loc[16];
#pragma unroll
    for (int j = 0; j < 4; ++j) {
      const float4 v = *(const float4*)&W[(size_t)(m0 + r) * NK + k0 + q * 16 + j * 4];
      loc[j * 4 + 0] = f2bf(v.x); loc[j * 4 + 1] = f2bf(v.y);
      loc[j * 4 + 2] = f2bf(v.z); loc[j * 4 + 3] = f2bf(v.w);
    }
#pragma unroll
    for (int jj = 0; jj < 16; ++jj) tile[r][q * 16 + jj] = loc[jj];
    __syncthreads();
    const int kk = tid >> 2, qq = tid & 3;
#pragma unroll
    for (int j = 0; j < 4; ++j) {
      ushort4 o;
      o.x = tile[qq * 16 + j * 4 + 0][kk];
      o.y = tile[qq * 16 + j * 4 + 1][kk];
      o.z = tile[qq * 16 + j * 4 + 2][kk];
      o.w = tile[qq * 16 + j * 4 + 3][kk];
      *(ushort4*)&Wt[(size_t)(k0 + kk) * NM + m0 + qq * 16 + j * 4] = o;
    }
  } else {
    // ---- Q 128^2 tile: 64 blocks (8x8), 4 waves as 2x2 of 64x64 ----
    ushort_t* As = (ushort_t*)smem;            // [128][64] bf16, 16 KB
    ushort_t* Bs = (ushort_t*)(smem + 16384);  // [128][64] bf16, 16 KB
    const int bq = b - 1536;
    const int i0 = (bq >> 3) * 128, j0 = (bq & 7) * 128;
    const int w = tid >> 6, l = tid & 63;
    const int wm = w >> 1, wn = w & 1;
    const int l15 = l & 15, l16 = l >> 4;
    const int qr = tid >> 1;                   // staging row 0..127
    const int qh = (tid & 1) * 32;             // staging col half

    f32x4 acc[4][4];
#pragma unroll
    for (int m = 0; m < 4; ++m)
#pragma unroll
      for (int n = 0; n < 4; ++n)
        acc[m][n] = (f32x4){0.f, 0.f, 0.f, 0.f};

    for (int k0 = 0; k0 < NK; k0 += 64) {
      // reg-stage 32 f32 per operand per thread, convert with manual RNE f2bf
      float4 va[8], vb[8];
      const float* pa = W + (size_t)(i0 + qr) * NK + k0 + qh;
      const float* pb = W + (size_t)(j0 + qr) * NK + k0 + qh;
#pragma unroll
      for (int j = 0; j < 8; ++j) {
        va[j] = *(const float4*)(pa + j * 4);
        vb[j] = *(const float4*)(pb + j * 4);
      }
      __syncthreads();   // prior MFMA LDS reads done before overwrite
#pragma unroll
      for (int j = 0; j < 8; ++j) {
        ushort4 oa, ob;
        oa.x = f2bf(va[j].x); oa.y = f2bf(va[j].y);
        oa.z = f2bf(va[j].z); oa.w = f2bf(va[j].w);
        ob.x = f2bf(vb[j].x); ob.y = f2bf(vb[j].y);
        ob.z = f2bf(vb[j].z); ob.w = f2bf(vb[j].w);
        *(ushort4*)&As[qr * 64 + qh + j * 4] = oa;
        *(ushort4*)&Bs[qr * 64 + qh + j * 4] = ob;
      }
      __syncthreads();
#pragma unroll
      for (int ks = 0; ks < 2; ++ks) {
        bf16x8 af[4], bfr[4];
#pragma unroll
        for (int m = 0; m < 4; ++m)
          af[m] = *(const bf16x8*)&As[(wm * 64 + m * 16 + l15) * 64 + ks * 32 + l16 * 8];
#pragma unroll
        for (int n = 0; n < 4; ++n)
          bfr[n] = *(const bf16x8*)&Bs[(wn * 64 + n * 16 + l15) * 64 + ks * 32 + l16 * 8];
#pragma unroll
        for (int m = 0; m < 4; ++m)
#pragma unroll
          for (int n = 0; n < 4; ++n)
            acc[m][n] = __builtin_amdgcn_mfma_f32_16x16x32_bf16(af[m], bfr[n], acc[m][n], 0, 0, 0);
      }
    }
    // C/D layout: col = lane&15, row = (lane>>4)*4 + q
#pragma unroll
    for (int m = 0; m < 4; ++m)
#pragma unroll
      for (int n = 0; n < 4; ++n) {
        const int gr0 = i0 + wm * 64 + m * 16 + l16 * 4;
        const int gc  = j0 + wn * 64 + n * 16 + l15;
#pragma unroll
        for (int q = 0; q < 4; ++q)
          Qbf[(size_t)(gr0 + q) * NM + gc] = f2bf(acc[m][n][q]);
      }
  }
}

// ============== 256xBN 8-phase deep-pipelined GEMM (finals) ==================
// C = Aop * Bop^T, tile 256xBN, BK=64, 512 threads (8 waves, 2Mx4N).
// Steady iter (2 K-tiles): 8 phases {ds_read subtile | stage 1 half-tile |
// barrier | lgkmcnt(0) | setprio+16 MFMA | [vmcnt] | barrier}; counted vmcnt
// at ph4/ph8 only. Last iteration peeled: quadrant stores overlap ph5-8.
// XOR swizzle byte^=(row&7)<<4 : inverse-swizzled global src, swizzled ds_read.
// outf = alpha*C (f32), alpha compile-time.
template<int BN>
__global__ __launch_bounds__(512, 2)
void gemm8ph(const ushort_t* __restrict__ Aop, const ushort_t* __restrict__ Bop,
             int KK, int njb, int outld, float* __restrict__ outf)
{
  constexpr int WN  = BN / 4;    // wave N extent (64 or 32)
  constexpr int NFR = BN / 64;   // B frags per wave (4 or 2)

  const int tid = threadIdx.x;
  const int w = tid >> 6, l = tid & 63;
  const int wm = w >> 2, wn = w & 3;
  // XCD-aware swizzle (grid % 8 == 0)
  const int wg = (blockIdx.x & 7) * ((int)gridDim.x >> 3) + ((int)blockIdx.x >> 3);
  const int bi = wg / njb, bj = wg % njb;
  const int i0 = bi * 256, j0 = bj * BN;
  const int l15 = l & 15, l16 = l >> 4;
  const int srow8 = l >> 3;          // lane row-in-8 for staging
  const int scb   = (l & 7) << 4;    // lane byte col for staging

  const float al = alpha_const();

  __shared__ __align__(1024) ushort_t ldsA[2][256 * 64];
  __shared__ __align__(1024) ushort_t ldsB[2][BN * 64];

  f32x4 acc[8][NFR];
#pragma unroll
  for (int m = 0; m < 8; ++m)
#pragma unroll
    for (int n = 0; n < NFR; ++n)
      acc[m][n] = (f32x4){0.f, 0.f, 0.f, 0.f};
  bf16x8 Bf[NFR][2];

  auto SH2 = [&](ushort_t* lb, const ushort_t* g0) {   // 128-row half
#pragma unroll
    for (int c = 0; c < 2; ++c) {
      const int row = (w * 2 + c) * 8 + srow8;
      const int sc = (scb ^ ((row & 7) << 4)) >> 1;
      gload_lds16(g0 + (size_t)row * (size_t)KK + sc, lb + (w * 2 + c) * 512);
    }
  };
  auto SH1 = [&](ushort_t* lb, const ushort_t* g0) {   // 64-row half
    const int row = w * 8 + srow8;
    const int sc = (scb ^ ((row & 7) << 4)) >> 1;
    gload_lds16(g0 + (size_t)row * (size_t)KK + sc, lb + w * 512);
  };
  auto stA = [&](int buf, int half, int kt) {
    SH2(&ldsA[buf][half * (128 * 64)],
        Aop + (size_t)(i0 + half * 128) * (size_t)KK + (size_t)kt * 64);
  };
  auto stB = [&](int buf, int half, int kt) {
    if constexpr (BN == 256)
      SH2(&ldsB[buf][half * (128 * 64)],
          Bop + (size_t)(j0 + half * 128) * (size_t)KK + (size_t)kt * 64);
    else
      SH1(&ldsB[buf][half * (64 * 64)],
          Bop + (size_t)(j0 + half * 64) * (size_t)KK + (size_t)kt * 64);
  };
  auto rdA = [&](int buf, int R, int ks) -> bf16x8 {
    const int bc = ((ks * 64 + l16 * 16) ^ ((R & 7) << 4)) >> 1;
    return *(const bf16x8*)&ldsA[buf][R * 64 + bc];
  };
  auto rdB = [&](int buf, int R, int ks) -> bf16x8 {
    const int bc = ((ks * 64 + l16 * 16) ^ ((R & 7) << 4)) >> 1;
    return *(const bf16x8*)&ldsB[buf][R * 64 + bc];
  };

#define VMC_STEADY() do { \
    if constexpr (BN == 256) asm volatile("s_waitcnt vmcnt(4)" ::: "memory"); \
    else                     asm volatile("s_waitcnt vmcnt(2)" ::: "memory"); } while (0)

// store one C-quadrant (overlapped into peeled phases)
#define STOREQ(qd)                                                          \
  do {                                                                      \
    _Pragma("unroll")                                                       \
    for (int mm = 0; mm < 2; ++mm) {                                        \
      const int m = (qd) * 2 + mm;                                          \
      const int gr0 = i0 + wm * 128 + m * 16 + l16 * 4;                     \
      _Pragma("unroll")                                                     \
      for (int n = 0; n < NFR; ++n) {                                       \
        const int gc = j0 + wn * WN + n * 16 + l15;                         \
        _Pragma("unroll")                                                   \
        for (int qq = 0; qq < 4; ++qq) {                                    \
          const size_t idx = (size_t)(gr0 + qq) * (size_t)outld + gc;       \
          outf[idx] = al * acc[m][n][qq];                                   \
        }                                                                   \
      }                                                                     \
    }                                                                       \
  } while (0)

  // PHASE: LB=load Bf from bufc; STG=stage stmt; VM: 0 none 1 steady 2 drain;
  // EPI = post-MFMA statement (stores)
#define PHASE(bufc, q, LB, STG, VM, EPI)                                    \
  do {                                                                      \
    if (LB) {                                                               \
      _Pragma("unroll")                                                     \
      for (int n = 0; n < NFR; ++n) {                                       \
        Bf[n][0] = rdB(bufc, wn * WN + n * 16 + l15, 0);                    \
        Bf[n][1] = rdB(bufc, wn * WN + n * 16 + l15, 1);                    \
      }                                                                     \
    }                                                                       \
    bf16x8 a00 = rdA(bufc, wm * 128 + ((q) * 2 + 0) * 16 + l15, 0);         \
    bf16x8 a01 = rdA(bufc, wm * 128 + ((q) * 2 + 0) * 16 + l15, 1);         \
    bf16x8 a10 = rdA(bufc, wm * 128 + ((q) * 2 + 1) * 16 + l15, 0);         \
    bf16x8 a11 = rdA(bufc, wm * 128 + ((q) * 2 + 1) * 16 + l15, 1);         \
    STG;                                                                    \
    if (LB && BN == 256) asm volatile("s_waitcnt lgkmcnt(8)" ::: "memory"); \
    __builtin_amdgcn_s_barrier();                                           \
    asm volatile("s_waitcnt lgkmcnt(0)" ::: "memory");                      \
    __builtin_amdgcn_sched_barrier(0);                                      \
    __builtin_amdgcn_s_setprio(1);                                          \
    _Pragma("unroll")                                                       \
    for (int n = 0; n < NFR; ++n) {                                         \
      acc[(q) * 2 + 0][n] = __builtin_amdgcn_mfma_f32_16x16x32_bf16(        \
          a00, Bf[n][0], acc[(q) * 2 + 0][n], 0, 0, 0);                     \
      acc[(q) * 2 + 0][n] = __builtin_amdgcn_mfma_f32_16x16x32_bf16(        \
          a01, Bf[n][1], acc[(q) * 2 + 0][n], 0, 0, 0);                     \
      acc[(q) * 2 + 1][n] = __builtin_amdgcn_mfma_f32_16x16x32_bf16(        \
          a10, Bf[n][0], acc[(q) * 2 + 1][n], 0, 0, 0);                     \
      acc[(q) * 2 + 1][n] = __builtin_amdgcn_mfma_f32_16x16x32_bf16(        \
          a11, Bf[n][1], acc[(q) * 2 + 1][n], 0, 0, 0);                     \
    }                                                                       \
    __builtin_amdgcn_s_setprio(0);                                          \
    EPI;                                                                    \
    {                                                                       \
      const int _vm = (VM);                                                 \
      if (_vm == 1) VMC_STEADY();                                           \
      else if (_vm == 2) asm volatile("s_waitcnt vmcnt(0)" ::: "memory");   \
    }                                                                       \
    __builtin_amdgcn_s_barrier();                                           \
    __builtin_amdgcn_sched_barrier(0);                                      \
  } while (0)

  const int nt = KK >> 6;        // K-tiles (even, >= 4)
  const int nit = nt >> 1;

  // prologue: buf0 <- tile0 (A+B), buf1.B <- tile1
  stA(0, 0, 0); stA(0, 1, 0); stB(0, 0, 0); stB(0, 1, 0);
  stB(1, 0, 1); stB(1, 1, 1);
  VMC_STEADY();
  __builtin_amdgcn_s_barrier();
  __builtin_amdgcn_sched_barrier(0);

#pragma unroll 1
  for (int it = 0; it < nit - 1; ++it) {
    const int t1 = 2 * it + 1, t2 = 2 * it + 2, t3 = 2 * it + 3;  // all < nt
    PHASE(0, 0, true,  { stA(1, 0, t1); }, 0, );            // ph1
    PHASE(0, 1, false, { stA(1, 1, t1); }, 0, );            // ph2
    PHASE(0, 2, false, { stB(0, 0, t2); }, 0, );            // ph3
    PHASE(0, 3, false, { stB(0, 1, t2); }, 1, );            // ph4
    PHASE(1, 0, true,  { stA(0, 0, t2); }, 0, );            // ph5
    PHASE(1, 1, false, { stA(0, 1, t2); }, 0, );            // ph6
    PHASE(1, 2, false, { stB(1, 0, t3); }, 0, );            // ph7
    PHASE(1, 3, false, { stB(1, 1, t3); }, 1, );            // ph8
  }
  {  // peeled final iteration: stores overlap ph5-8
    const int t1 = nt - 1;
    PHASE(0, 0, true,  { stA(1, 0, t1); }, 0, );
    PHASE(0, 1, false, { stA(1, 1, t1); }, 0, );
    PHASE(0, 2, false, { }, 0, );
    PHASE(0, 3, false, { }, 2, );                           // drain A1+B1
    PHASE(1, 0, true,  { }, 0, STOREQ(0));
    PHASE(1, 1, false, { }, 0, STOREQ(1));
    PHASE(1, 2, false, { }, 0, STOREQ(2));
    PHASE(1, 3, false, { }, 0, STOREQ(3));
  }
#undef PHASE
#undef STOREQ
#undef VMC_STEADY
}

extern "C" void kernel_launch(void* const* d_in, const int* in_sizes, int n_in,
                              void* d_out, int out_size, void* d_ws, size_t ws_size,
                              hipStream_t stream) {
  (void)in_sizes; (void)n_in; (void)out_size; (void)ws_size;
  const float* img = (const float*)d_in[0];   // [8192][1024] f32
  const float* W   = (const float*)d_in[1];   // [1024][2048] f32, cols unit-norm

  float* Rr = (float*)d_out;                   // r = alpha*(img@W), f32 [8192][2048]
  float* Pp = Rr + (size_t)NB * NK;            // pred = alpha*(img@Q), f32 [8192][1024]

  char* ws = (char*)d_ws;
  ushort_t* imgbf = (ushort_t*)(ws + 0);          // 16,777,216 B [8192][1024]
  ushort_t* Wt    = (ushort_t*)(ws + 16777216);   //  4,194,304 B [2048][1024]
  ushort_t* Qbf   = (ushort_t*)(ws + 20971520);   //  2,097,152 B [1024][1024]

  // prep: img->bf16 (0-1023), W->Wt (1024-1535), Q 128^2 tiles (1536-1599)
  prep_k<<<1600, 256, 0, stream>>>(img, W, imgbf, Wt, Qbf);

  // r = alpha*(img @ W).  32x8 = 256 blocks, BN=256, K=1024 — one full round.
  gemm8ph<256><<<256, 512, 0, stream>>>(imgbf, Wt, NM, 8, NK, Rr);
  // pred = alpha*(img @ Q) (Q symmetric). 256 blocks, BN=128 — one full round.
  gemm8ph<128><<<256, 512, 0, stream>>>(imgbf, Qbf, NM, 8, NM, Pp);
}

// Round 12
// 103.269 us; speedup vs baseline: 1.7050x; 1.7050x over previous
//
#include <hip/hip_runtime.h>

// ---- problem constants ----
#define NB 8192      // batch rows
#define NM 1024      // image dim
#define NK 2048      // dictionary size

typedef unsigned short ushort_t;
using bf16x8 = __attribute__((ext_vector_type(8))) short;
using f32x4  = __attribute__((ext_vector_type(4))) float;

// T = 101 provably: accept at t=101 holds for all b/a > 0; flip at t=100
// would need b/a >= ~4e6 but b/a <= tr(W W^T) = 2048 (unit-norm cols).
// Reproduce solve_k's exact double arithmetic, then cast.
__device__ __forceinline__ float alpha_const() {
  const double s = 0.1 * (2.0 / 8388608.0);
  return (float)(101.0 * s);
}

__device__ __forceinline__ ushort_t f2bf(float f) {
  union { float f; unsigned u; } v; v.f = f;
  unsigned r = (v.u + 0x7FFFu + ((v.u >> 16) & 1u)) >> 16;  // RNE
  return (ushort_t)r;
}

__device__ __forceinline__ void gload_lds16(const void* g, void* l) {
  __builtin_amdgcn_global_load_lds(
      (const __attribute__((address_space(1))) unsigned int*)g,
      (__attribute__((address_space(3))) unsigned int*)l, 16, 0, 0);
}

// ============ fused prep: img->bf16, W->Wbf + tiled-transpose Wt =============
__global__ __launch_bounds__(256)
void conv_all_k(const float* __restrict__ img, const float* __restrict__ W,
                ushort_t* __restrict__ imgbf, ushort_t* __restrict__ Wbf,
                ushort_t* __restrict__ Wt)
{
  const int tid = threadIdx.x;
  const int b = blockIdx.x;
  if (b < 512) {
    const int base = b * 4096;
#pragma unroll
    for (int i = 0; i < 16; ++i) {
      const int idx = base + i * 256 + tid;
      const float4 v = ((const float4*)img)[idx];
      ushort4 o;
      o.x = f2bf(v.x); o.y = f2bf(v.y); o.z = f2bf(v.z); o.w = f2bf(v.w);
      ((ushort4*)imgbf)[idx] = o;
    }
  } else {
    __shared__ ushort_t tile[64][65];
    const int bW = b - 512;                       // 512 tiles: 16(m) x 32(k)
    const int m0 = (bW >> 5) * 64, k0 = (bW & 31) * 64;
    const int r = tid >> 2, q = tid & 3;
    ushort_t loc[16];
#pragma unroll
    for (int j = 0; j < 4; ++j) {
      const float4 v = *(const float4*)&W[(size_t)(m0 + r) * NK + k0 + q * 16 + j * 4];
      loc[j * 4 + 0] = f2bf(v.x); loc[j * 4 + 1] = f2bf(v.y);
      loc[j * 4 + 2] = f2bf(v.z); loc[j * 4 + 3] = f2bf(v.w);
    }
#pragma unroll
    for (int j = 0; j < 4; ++j) {
      ushort4 o;
      o.x = loc[j * 4 + 0]; o.y = loc[j * 4 + 1];
      o.z = loc[j * 4 + 2]; o.w = loc[j * 4 + 3];
      *(ushort4*)&Wbf[(size_t)(m0 + r) * NK + k0 + q * 16 + j * 4] = o;
    }
#pragma unroll
    for (int jj = 0; jj < 16; ++jj) tile[r][q * 16 + jj] = loc[jj];
    __syncthreads();
    const int kk = tid >> 2, qq = tid & 3;
#pragma unroll
    for (int j = 0; j < 4; ++j) {
      ushort4 o;
      o.x = tile[qq * 16 + j * 4 + 0][kk];
      o.y = tile[qq * 16 + j * 4 + 1][kk];
      o.z = tile[qq * 16 + j * 4 + 2][kk];
      o.w = tile[qq * 16 + j * 4 + 3][kk];
      *(ushort4*)&Wt[(size_t)(k0 + kk) * NM + m0 + qq * 16 + j * 4] = o;
    }
  }
}

// ============ Q = bf16(W @ W^T), 64x64 tiles, 256 blocks (full GPU) ==========
// m97-style staging (gload_lds 16B), 4 waves as 2x2 of 32x32, K-step 64.
// Same per-element K-accumulation order as prior rounds -> bitwise-stable Q.
__global__ __launch_bounds__(256)
void qk64(const ushort_t* __restrict__ Wbf, ushort_t* __restrict__ Qbf)
{
  const int tid = threadIdx.x;
  const int w = tid >> 6, l = tid & 63;
  const int wm2 = w >> 1, wn2 = w & 1;
  const int bi = blockIdx.x >> 4, bj = blockIdx.x & 15;
  const int i0 = bi * 64, j0 = bj * 64;
  const int l15 = l & 15, l16 = l >> 4;
  const int lr = l >> 3;
  const int lc = (l & 7) * 8;

  __shared__ __align__(128) ushort_t As[64 * 64];
  __shared__ __align__(128) ushort_t Bs[64 * 64];

  f32x4 acc[2][2];
#pragma unroll
  for (int m = 0; m < 2; ++m)
#pragma unroll
    for (int n = 0; n < 2; ++n)
      acc[m][n] = (f32x4){0.f, 0.f, 0.f, 0.f};

  for (int k0 = 0; k0 < NK; k0 += 64) {
#pragma unroll
    for (int c = 0; c < 2; ++c) {
      const int rr = c * 32 + w * 8 + lr;
      const int base = c * 2048 + w * 512;
      gload_lds16(Wbf + (size_t)(i0 + rr) * NK + k0 + lc, &As[base]);
      gload_lds16(Wbf + (size_t)(j0 + rr) * NK + k0 + lc, &Bs[base]);
    }
    __syncthreads();
#pragma unroll
    for (int ks = 0; ks < 2; ++ks) {
      bf16x8 af[2], bfr[2];
#pragma unroll
      for (int m = 0; m < 2; ++m)
        af[m] = *(const bf16x8*)&As[(wm2 * 32 + m * 16 + l15) * 64 + ks * 32 + l16 * 8];
#pragma unroll
      for (int n = 0; n < 2; ++n)
        bfr[n] = *(const bf16x8*)&Bs[(wn2 * 32 + n * 16 + l15) * 64 + ks * 32 + l16 * 8];
#pragma unroll
      for (int m = 0; m < 2; ++m)
#pragma unroll
        for (int n = 0; n < 2; ++n)
          acc[m][n] = __builtin_amdgcn_mfma_f32_16x16x32_bf16(af[m], bfr[n], acc[m][n], 0, 0, 0);
    }
    __syncthreads();
  }

  // C/D layout: col = lane&15, row = (lane>>4)*4 + q
#pragma unroll
  for (int m = 0; m < 2; ++m)
#pragma unroll
    for (int n = 0; n < 2; ++n) {
      const int gr0 = i0 + wm2 * 32 + m * 16 + l16 * 4;
      const int gc  = j0 + wn2 * 32 + n * 16 + l15;
#pragma unroll
      for (int q = 0; q < 4; ++q)
        Qbf[(size_t)(gr0 + q) * NM + gc] = f2bf(acc[m][n][q]);
    }
}

// ============== 256xBN 8-phase deep-pipelined GEMM (finals) ==================
// C = Aop * Bop^T, tile 256xBN, BK=64, 512 threads (8 waves, 2Mx4N).
// Steady iter (2 K-tiles): 8 phases {ds_read subtile | stage 1 half-tile |
// barrier | lgkmcnt(0) | setprio+16 MFMA | [vmcnt] | barrier}; counted vmcnt
// at ph4/ph8 only. Last iteration peeled: quadrant stores overlap ph5-8.
// XOR swizzle byte^=(row&7)<<4 : inverse-swizzled global src, swizzled ds_read.
// outf = alpha*C (f32), alpha compile-time.
template<int BN>
__global__ __launch_bounds__(512, 2)
void gemm8ph(const ushort_t* __restrict__ Aop, const ushort_t* __restrict__ Bop,
             int KK, int njb, int outld, float* __restrict__ outf)
{
  constexpr int WN  = BN / 4;    // wave N extent (64 or 32)
  constexpr int NFR = BN / 64;   // B frags per wave (4 or 2)

  const int tid = threadIdx.x;
  const int w = tid >> 6, l = tid & 63;
  const int wm = w >> 2, wn = w & 3;
  // XCD-aware swizzle (grid % 8 == 0)
  const int wg = (blockIdx.x & 7) * ((int)gridDim.x >> 3) + ((int)blockIdx.x >> 3);
  const int bi = wg / njb, bj = wg % njb;
  const int i0 = bi * 256, j0 = bj * BN;
  const int l15 = l & 15, l16 = l >> 4;
  const int srow8 = l >> 3;          // lane row-in-8 for staging
  const int scb   = (l & 7) << 4;    // lane byte col for staging

  const float al = alpha_const();

  __shared__ __align__(1024) ushort_t ldsA[2][256 * 64];
  __shared__ __align__(1024) ushort_t ldsB[2][BN * 64];

  f32x4 acc[8][NFR];
#pragma unroll
  for (int m = 0; m < 8; ++m)
#pragma unroll
    for (int n = 0; n < NFR; ++n)
      acc[m][n] = (f32x4){0.f, 0.f, 0.f, 0.f};
  bf16x8 Bf[NFR][2];

  auto SH2 = [&](ushort_t* lb, const ushort_t* g0) {   // 128-row half
#pragma unroll
    for (int c = 0; c < 2; ++c) {
      const int row = (w * 2 + c) * 8 + srow8;
      const int sc = (scb ^ ((row & 7) << 4)) >> 1;
      gload_lds16(g0 + (size_t)row * (size_t)KK + sc, lb + (w * 2 + c) * 512);
    }
  };
  auto SH1 = [&](ushort_t* lb, const ushort_t* g0) {   // 64-row half
    const int row = w * 8 + srow8;
    const int sc = (scb ^ ((row & 7) << 4)) >> 1;
    gload_lds16(g0 + (size_t)row * (size_t)KK + sc, lb + w * 512);
  };
  auto stA = [&](int buf, int half, int kt) {
    SH2(&ldsA[buf][half * (128 * 64)],
        Aop + (size_t)(i0 + half * 128) * (size_t)KK + (size_t)kt * 64);
  };
  auto stB = [&](int buf, int half, int kt) {
    if constexpr (BN == 256)
      SH2(&ldsB[buf][half * (128 * 64)],
          Bop + (size_t)(j0 + half * 128) * (size_t)KK + (size_t)kt * 64);
    else
      SH1(&ldsB[buf][half * (64 * 64)],
          Bop + (size_t)(j0 + half * 64) * (size_t)KK + (size_t)kt * 64);
  };
  auto rdA = [&](int buf, int R, int ks) -> bf16x8 {
    const int bc = ((ks * 64 + l16 * 16) ^ ((R & 7) << 4)) >> 1;
    return *(const bf16x8*)&ldsA[buf][R * 64 + bc];
  };
  auto rdB = [&](int buf, int R, int ks) -> bf16x8 {
    const int bc = ((ks * 64 + l16 * 16) ^ ((R & 7) << 4)) >> 1;
    return *(const bf16x8*)&ldsB[buf][R * 64 + bc];
  };

#define VMC_STEADY() do { \
    if constexpr (BN == 256) asm volatile("s_waitcnt vmcnt(4)" ::: "memory"); \
    else                     asm volatile("s_waitcnt vmcnt(2)" ::: "memory"); } while (0)

// store one C-quadrant (overlapped into peeled phases)
#define STOREQ(qd)                                                          \
  do {                                                                      \
    _Pragma("unroll")                                                       \
    for (int mm = 0; mm < 2; ++mm) {                                        \
      const int m = (qd) * 2 + mm;                                          \
      const int gr0 = i0 + wm * 128 + m * 16 + l16 * 4;                     \
      _Pragma("unroll")                                                     \
      for (int n = 0; n < NFR; ++n) {                                       \
        const int gc = j0 + wn * WN + n * 16 + l15;                         \
        _Pragma("unroll")                                                   \
        for (int qq = 0; qq < 4; ++qq) {                                    \
          const size_t idx = (size_t)(gr0 + qq) * (size_t)outld + gc;       \
          outf[idx] = al * acc[m][n][qq];                                   \
        }                                                                   \
      }                                                                     \
    }                                                                       \
  } while (0)

  // PHASE: LB=load Bf from bufc; STG=stage stmt; VM: 0 none 1 steady 2 drain;
  // EPI = post-MFMA statement (stores)
#define PHASE(bufc, q, LB, STG, VM, EPI)                                    \
  do {                                                                      \
    if (LB) {                                                               \
      _Pragma("unroll")                                                     \
      for (int n = 0; n < NFR; ++n) {                                       \
        Bf[n][0] = rdB(bufc, wn * WN + n * 16 + l15, 0);                    \
        Bf[n][1] = rdB(bufc, wn * WN + n * 16 + l15, 1);                    \
      }                                                                     \
    }                                                                       \
    bf16x8 a00 = rdA(bufc, wm * 128 + ((q) * 2 + 0) * 16 + l15, 0);         \
    bf16x8 a01 = rdA(bufc, wm * 128 + ((q) * 2 + 0) * 16 + l15, 1);         \
    bf16x8 a10 = rdA(bufc, wm * 128 + ((q) * 2 + 1) * 16 + l15, 0);         \
    bf16x8 a11 = rdA(bufc, wm * 128 + ((q) * 2 + 1) * 16 + l15, 1);         \
    STG;                                                                    \
    if (LB && BN == 256) asm volatile("s_waitcnt lgkmcnt(8)" ::: "memory"); \
    __builtin_amdgcn_s_barrier();                                           \
    asm volatile("s_waitcnt lgkmcnt(0)" ::: "memory");                      \
    __builtin_amdgcn_sched_barrier(0);                                      \
    __builtin_amdgcn_s_setprio(1);                                          \
    _Pragma("unroll")                                                       \
    for (int n = 0; n < NFR; ++n) {                                         \
      acc[(q) * 2 + 0][n] = __builtin_amdgcn_mfma_f32_16x16x32_bf16(        \
          a00, Bf[n][0], acc[(q) * 2 + 0][n], 0, 0, 0);                     \
      acc[(q) * 2 + 0][n] = __builtin_amdgcn_mfma_f32_16x16x32_bf16(        \
          a01, Bf[n][1], acc[(q) * 2 + 0][n], 0, 0, 0);                     \
      acc[(q) * 2 + 1][n] = __builtin_amdgcn_mfma_f32_16x16x32_bf16(        \
          a10, Bf[n][0], acc[(q) * 2 + 1][n], 0, 0, 0);                     \
      acc[(q) * 2 + 1][n] = __builtin_amdgcn_mfma_f32_16x16x32_bf16(        \
          a11, Bf[n][1], acc[(q) * 2 + 1][n], 0, 0, 0);                     \
    }                                                                       \
    __builtin_amdgcn_s_setprio(0);                                          \
    EPI;                                                                    \
    {                                                                       \
      const int _vm = (VM);                                                 \
      if (_vm == 1) VMC_STEADY();                                           \
      else if (_vm == 2) asm volatile("s_waitcnt vmcnt(0)" ::: "memory");   \
    }                                                                       \
    __builtin_amdgcn_s_barrier();                                           \
    __builtin_amdgcn_sched_barrier(0);                                      \
  } while (0)

  const int nt = KK >> 6;        // K-tiles (even, >= 4)
  const int nit = nt >> 1;

  // prologue: buf0 <- tile0 (A+B), buf1.B <- tile1
  stA(0, 0, 0); stA(0, 1, 0); stB(0, 0, 0); stB(0, 1, 0);
  stB(1, 0, 1); stB(1, 1, 1);
  VMC_STEADY();
  __builtin_amdgcn_s_barrier();
  __builtin_amdgcn_sched_barrier(0);

#pragma unroll 1
  for (int it = 0; it < nit - 1; ++it) {
    const int t1 = 2 * it + 1, t2 = 2 * it + 2, t3 = 2 * it + 3;  // all < nt
    PHASE(0, 0, true,  { stA(1, 0, t1); }, 0, );            // ph1
    PHASE(0, 1, false, { stA(1, 1, t1); }, 0, );            // ph2
    PHASE(0, 2, false, { stB(0, 0, t2); }, 0, );            // ph3
    PHASE(0, 3, false, { stB(0, 1, t2); }, 1, );            // ph4
    PHASE(1, 0, true,  { stA(0, 0, t2); }, 0, );            // ph5
    PHASE(1, 1, false, { stA(0, 1, t2); }, 0, );            // ph6
    PHASE(1, 2, false, { stB(1, 0, t3); }, 0, );            // ph7
    PHASE(1, 3, false, { stB(1, 1, t3); }, 1, );            // ph8
  }
  {  // peeled final iteration: stores overlap ph5-8
    const int t1 = nt - 1;
    PHASE(0, 0, true,  { stA(1, 0, t1); }, 0, );
    PHASE(0, 1, false, { stA(1, 1, t1); }, 0, );
    PHASE(0, 2, false, { }, 0, );
    PHASE(0, 3, false, { }, 2, );                           // drain A1+B1
    PHASE(1, 0, true,  { }, 0, STOREQ(0));
    PHASE(1, 1, false, { }, 0, STOREQ(1));
    PHASE(1, 2, false, { }, 0, STOREQ(2));
    PHASE(1, 3, false, { }, 0, STOREQ(3));
  }
#undef PHASE
#undef STOREQ
#undef VMC_STEADY
}

extern "C" void kernel_launch(void* const* d_in, const int* in_sizes, int n_in,
                              void* d_out, int out_size, void* d_ws, size_t ws_size,
                              hipStream_t stream) {
  (void)in_sizes; (void)n_in; (void)out_size; (void)ws_size;
  const float* img = (const float*)d_in[0];   // [8192][1024] f32
  const float* W   = (const float*)d_in[1];   // [1024][2048] f32, cols unit-norm

  float* Rr = (float*)d_out;                   // r = alpha*(img@W), f32 [8192][2048]
  float* Pp = Rr + (size_t)NB * NK;            // pred = alpha*(img@Q), f32 [8192][1024]

  char* ws = (char*)d_ws;
  ushort_t* imgbf = (ushort_t*)(ws + 0);          // 16,777,216 B [8192][1024]
  ushort_t* Wt    = (ushort_t*)(ws + 16777216);   //  4,194,304 B [2048][1024]
  ushort_t* Wbf   = (ushort_t*)(ws + 20971520);   //  4,194,304 B [1024][2048]
  ushort_t* Qbf   = (ushort_t*)(ws + 25165824);   //  2,097,152 B [1024][1024]

  // prep: img->bf16 (blocks 0-511), W->Wbf+Wt tiled transpose (512-1023)
  conv_all_k<<<1024, 256, 0, stream>>>(img, W, imgbf, Wbf, Wt);

  // Q = bf16(W @ W^T): 16x16 = 256 blocks of 64x64 tiles, K=2048
  qk64<<<256, 256, 0, stream>>>(Wbf, Qbf);

  // r = alpha*(img @ W).  32x8 = 256 blocks, BN=256, K=1024 — one full round.
  gemm8ph<256><<<256, 512, 0, stream>>>(imgbf, Wt, NM, 8, NK, Rr);
  // pred = alpha*(img @ Q) (Q symmetric). 256 blocks, BN=128 — one full round.
  gemm8ph<128><<<256, 512, 0, stream>>>(imgbf, Qbf, NM, 8, NM, Pp);
}

// Round 13
// 101.418 us; speedup vs baseline: 1.7361x; 1.0183x over previous
//
#include <hip/hip_runtime.h>

// ---- problem constants ----
#define NB 8192      // batch rows
#define NM 1024      // image dim
#define NK 2048      // dictionary size

typedef unsigned short ushort_t;
using bf16x8 = __attribute__((ext_vector_type(8))) short;
using f32x4  = __attribute__((ext_vector_type(4))) float;

// T = 101 provably: accept at t=101 holds for all b/a > 0; flip at t=100
// would need b/a >= ~4e6 but b/a <= tr(W W^T) = 2048 (unit-norm cols).
__device__ __forceinline__ float alpha_const() {
  const double s = 0.1 * (2.0 / 8388608.0);
  return (float)(101.0 * s);
}

__device__ __forceinline__ ushort_t f2bf(float f) {
  union { float f; unsigned u; } v; v.f = f;
  unsigned r = (v.u + 0x7FFFu + ((v.u >> 16) & 1u)) >> 16;  // RNE
  return (ushort_t)r;
}

__device__ __forceinline__ void gload_lds16(const void* g, void* l) {
  __builtin_amdgcn_global_load_lds(
      (const __attribute__((address_space(1))) unsigned int*)g,
      (__attribute__((address_space(3))) unsigned int*)l, 16, 0, 0);
}

// ============ prep W: W->Wbf + tiled-transpose Wt (512 blocks) ===============
__global__ __launch_bounds__(256)
void prep_w_k(const float* __restrict__ W, ushort_t* __restrict__ Wbf,
              ushort_t* __restrict__ Wt)
{
  __shared__ ushort_t tile[64][65];
  const int tid = threadIdx.x;
  const int bW = blockIdx.x;                    // 512 tiles: 16(m) x 32(k)
  const int m0 = (bW >> 5) * 64, k0 = (bW & 31) * 64;
  const int r = tid >> 2, q = tid & 3;
  ushort_t loc[16];
#pragma unroll
  for (int j = 0; j < 4; ++j) {
    const float4 v = *(const float4*)&W[(size_t)(m0 + r) * NK + k0 + q * 16 + j * 4];
    loc[j * 4 + 0] = f2bf(v.x); loc[j * 4 + 1] = f2bf(v.y);
    loc[j * 4 + 2] = f2bf(v.z); loc[j * 4 + 3] = f2bf(v.w);
  }
#pragma unroll
  for (int j = 0; j < 4; ++j) {
    ushort4 o;
    o.x = loc[j * 4 + 0]; o.y = loc[j * 4 + 1];
    o.z = loc[j * 4 + 2]; o.w = loc[j * 4 + 3];
    *(ushort4*)&Wbf[(size_t)(m0 + r) * NK + k0 + q * 16 + j * 4] = o;
  }
#pragma unroll
  for (int jj = 0; jj < 16; ++jj) tile[r][q * 16 + jj] = loc[jj];
  __syncthreads();
  const int kk = tid >> 2, qq = tid & 3;
#pragma unroll
  for (int j = 0; j < 4; ++j) {
    ushort4 o;
    o.x = tile[qq * 16 + j * 4 + 0][kk];
    o.y = tile[qq * 16 + j * 4 + 1][kk];
    o.z = tile[qq * 16 + j * 4 + 2][kk];
    o.w = tile[qq * 16 + j * 4 + 3][kk];
    *(ushort4*)&Wt[(size_t)(k0 + kk) * NM + m0 + qq * 16 + j * 4] = o;
  }
}

// ==== fused: Q = bf16(W@W^T) on blocks 0-255 (MFMA/L2-bound, dispatch first)
//      + img->bf16 on blocks 256-1279 (HBM-bound, backfills). Independent work;
//      complementary resources -> overlap. Both bodies byte-identical to the
//      proven qk64 / img-convert loops -> outputs bitwise identical. ==========
__global__ __launch_bounds__(256)
void qimg_k(const ushort_t* __restrict__ Wbf, ushort_t* __restrict__ Qbf,
            const float* __restrict__ img, ushort_t* __restrict__ imgbf)
{
  __shared__ __align__(128) ushort_t As[64 * 64];
  __shared__ __align__(128) ushort_t Bs[64 * 64];
  const int tid = threadIdx.x;
  const int b = blockIdx.x;

  if (b >= 256) {
    // ---- img -> bf16: 1024 blocks x 8 float4/thread ----
    const int base = (b - 256) * 2048;
#pragma unroll
    for (int i = 0; i < 8; ++i) {
      const int idx = base + i * 256 + tid;
      const float4 v = ((const float4*)img)[idx];
      ushort4 o;
      o.x = f2bf(v.x); o.y = f2bf(v.y); o.z = f2bf(v.z); o.w = f2bf(v.w);
      ((ushort4*)imgbf)[idx] = o;
    }
    return;
  }

  // ---- Q 64x64 tile (qk64 body): 4 waves as 2x2 of 32x32, K-step 64 ----
  const int w = tid >> 6, l = tid & 63;
  const int wm2 = w >> 1, wn2 = w & 1;
  const int bi = b >> 4, bj = b & 15;
  const int i0 = bi * 64, j0 = bj * 64;
  const int l15 = l & 15, l16 = l >> 4;
  const int lr = l >> 3;
  const int lc = (l & 7) * 8;

  f32x4 acc[2][2];
#pragma unroll
  for (int m = 0; m < 2; ++m)
#pragma unroll
    for (int n = 0; n < 2; ++n)
      acc[m][n] = (f32x4){0.f, 0.f, 0.f, 0.f};

  for (int k0 = 0; k0 < NK; k0 += 64) {
#pragma unroll
    for (int c = 0; c < 2; ++c) {
      const int rr = c * 32 + w * 8 + lr;
      const int base = c * 2048 + w * 512;
      gload_lds16(Wbf + (size_t)(i0 + rr) * NK + k0 + lc, &As[base]);
      gload_lds16(Wbf + (size_t)(j0 + rr) * NK + k0 + lc, &Bs[base]);
    }
    __syncthreads();
#pragma unroll
    for (int ks = 0; ks < 2; ++ks) {
      bf16x8 af[2], bfr[2];
#pragma unroll
      for (int m = 0; m < 2; ++m)
        af[m] = *(const bf16x8*)&As[(wm2 * 32 + m * 16 + l15) * 64 + ks * 32 + l16 * 8];
#pragma unroll
      for (int n = 0; n < 2; ++n)
        bfr[n] = *(const bf16x8*)&Bs[(wn2 * 32 + n * 16 + l15) * 64 + ks * 32 + l16 * 8];
#pragma unroll
      for (int m = 0; m < 2; ++m)
#pragma unroll
        for (int n = 0; n < 2; ++n)
          acc[m][n] = __builtin_amdgcn_mfma_f32_16x16x32_bf16(af[m], bfr[n], acc[m][n], 0, 0, 0);
    }
    __syncthreads();
  }

  // C/D layout: col = lane&15, row = (lane>>4)*4 + q
#pragma unroll
  for (int m = 0; m < 2; ++m)
#pragma unroll
    for (int n = 0; n < 2; ++n) {
      const int gr0 = i0 + wm2 * 32 + m * 16 + l16 * 4;
      const int gc  = j0 + wn2 * 32 + n * 16 + l15;
#pragma unroll
      for (int q = 0; q < 4; ++q)
        Qbf[(size_t)(gr0 + q) * NM + gc] = f2bf(acc[m][n][q]);
    }
}

// ============== 256xBN 8-phase deep-pipelined GEMM (finals) ==================
// C = Aop * Bop^T, tile 256xBN, BK=64, 512 threads (8 waves, 2Mx4N).
// Steady iter (2 K-tiles): 8 phases {ds_read subtile | stage 1 half-tile |
// barrier | lgkmcnt(0) | setprio+16 MFMA | [vmcnt] | barrier}; counted vmcnt
// at ph4/ph8 only. Last iteration peeled: quadrant stores overlap ph5-8.
// XOR swizzle byte^=(row&7)<<4 : inverse-swizzled global src, swizzled ds_read.
// outf = alpha*C (f32), alpha compile-time.
template<int BN>
__global__ __launch_bounds__(512, 2)
void gemm8ph(const ushort_t* __restrict__ Aop, const ushort_t* __restrict__ Bop,
             int KK, int njb, int outld, float* __restrict__ outf)
{
  constexpr int WN  = BN / 4;    // wave N extent (64 or 32)
  constexpr int NFR = BN / 64;   // B frags per wave (4 or 2)

  const int tid = threadIdx.x;
  const int w = tid >> 6, l = tid & 63;
  const int wm = w >> 2, wn = w & 3;
  // XCD-aware swizzle (grid % 8 == 0)
  const int wg = (blockIdx.x & 7) * ((int)gridDim.x >> 3) + ((int)blockIdx.x >> 3);
  const int bi = wg / njb, bj = wg % njb;
  const int i0 = bi * 256, j0 = bj * BN;
  const int l15 = l & 15, l16 = l >> 4;
  const int srow8 = l >> 3;          // lane row-in-8 for staging
  const int scb   = (l & 7) << 4;    // lane byte col for staging

  const float al = alpha_const();

  __shared__ __align__(1024) ushort_t ldsA[2][256 * 64];
  __shared__ __align__(1024) ushort_t ldsB[2][BN * 64];

  f32x4 acc[8][NFR];
#pragma unroll
  for (int m = 0; m < 8; ++m)
#pragma unroll
    for (int n = 0; n < NFR; ++n)
      acc[m][n] = (f32x4){0.f, 0.f, 0.f, 0.f};
  bf16x8 Bf[NFR][2];

  auto SH2 = [&](ushort_t* lb, const ushort_t* g0) {   // 128-row half
#pragma unroll
    for (int c = 0; c < 2; ++c) {
      const int row = (w * 2 + c) * 8 + srow8;
      const int sc = (scb ^ ((row & 7) << 4)) >> 1;
      gload_lds16(g0 + (size_t)row * (size_t)KK + sc, lb + (w * 2 + c) * 512);
    }
  };
  auto SH1 = [&](ushort_t* lb, const ushort_t* g0) {   // 64-row half
    const int row = w * 8 + srow8;
    const int sc = (scb ^ ((row & 7) << 4)) >> 1;
    gload_lds16(g0 + (size_t)row * (size_t)KK + sc, lb + w * 512);
  };
  auto stA = [&](int buf, int half, int kt) {
    SH2(&ldsA[buf][half * (128 * 64)],
        Aop + (size_t)(i0 + half * 128) * (size_t)KK + (size_t)kt * 64);
  };
  auto stB = [&](int buf, int half, int kt) {
    if constexpr (BN == 256)
      SH2(&ldsB[buf][half * (128 * 64)],
          Bop + (size_t)(j0 + half * 128) * (size_t)KK + (size_t)kt * 64);
    else
      SH1(&ldsB[buf][half * (64 * 64)],
          Bop + (size_t)(j0 + half * 64) * (size_t)KK + (size_t)kt * 64);
  };
  auto rdA = [&](int buf, int R, int ks) -> bf16x8 {
    const int bc = ((ks * 64 + l16 * 16) ^ ((R & 7) << 4)) >> 1;
    return *(const bf16x8*)&ldsA[buf][R * 64 + bc];
  };
  auto rdB = [&](int buf, int R, int ks) -> bf16x8 {
    const int bc = ((ks * 64 + l16 * 16) ^ ((R & 7) << 4)) >> 1;
    return *(const bf16x8*)&ldsB[buf][R * 64 + bc];
  };

#define VMC_STEADY() do { \
    if constexpr (BN == 256) asm volatile("s_waitcnt vmcnt(4)" ::: "memory"); \
    else                     asm volatile("s_waitcnt vmcnt(2)" ::: "memory"); } while (0)

// store one C-quadrant (overlapped into peeled phases)
#define STOREQ(qd)                                                          \
  do {                                                                      \
    _Pragma("unroll")                                                       \
    for (int mm = 0; mm < 2; ++mm) {                                        \
      const int m = (qd) * 2 + mm;                                          \
      const int gr0 = i0 + wm * 128 + m * 16 + l16 * 4;                     \
      _Pragma("unroll")                                                     \
      for (int n = 0; n < NFR; ++n) {                                       \
        const int gc = j0 + wn * WN + n * 16 + l15;                         \
        _Pragma("unroll")                                                   \
        for (int qq = 0; qq < 4; ++qq) {                                    \
          const size_t idx = (size_t)(gr0 + qq) * (size_t)outld + gc;       \
          outf[idx] = al * acc[m][n][qq];                                   \
        }                                                                   \
      }                                                                     \
    }                                                                       \
  } while (0)

  // PHASE: LB=load Bf from bufc; STG=stage stmt; VM: 0 none 1 steady 2 drain;
  // EPI = post-MFMA statement (stores)
#define PHASE(bufc, q, LB, STG, VM, EPI)                                    \
  do {                                                                      \
    if (LB) {                                                               \
      _Pragma("unroll")                                                     \
      for (int n = 0; n < NFR; ++n) {                                       \
        Bf[n][0] = rdB(bufc, wn * WN + n * 16 + l15, 0);                    \
        Bf[n][1] = rdB(bufc, wn * WN + n * 16 + l15, 1);                    \
      }                                                                     \
    }                                                                       \
    bf16x8 a00 = rdA(bufc, wm * 128 + ((q) * 2 + 0) * 16 + l15, 0);         \
    bf16x8 a01 = rdA(bufc, wm * 128 + ((q) * 2 + 0) * 16 + l15, 1);         \
    bf16x8 a10 = rdA(bufc, wm * 128 + ((q) * 2 + 1) * 16 + l15, 0);         \
    bf16x8 a11 = rdA(bufc, wm * 128 + ((q) * 2 + 1) * 16 + l15, 1);         \
    STG;                                                                    \
    if (LB && BN == 256) asm volatile("s_waitcnt lgkmcnt(8)" ::: "memory"); \
    __builtin_amdgcn_s_barrier();                                           \
    asm volatile("s_waitcnt lgkmcnt(0)" ::: "memory");                      \
    __builtin_amdgcn_sched_barrier(0);                                      \
    __builtin_amdgcn_s_setprio(1);                                          \
    _Pragma("unroll")                                                       \
    for (int n = 0; n < NFR; ++n) {                                         \
      acc[(q) * 2 + 0][n] = __builtin_amdgcn_mfma_f32_16x16x32_bf16(        \
          a00, Bf[n][0], acc[(q) * 2 + 0][n], 0, 0, 0);                     \
      acc[(q) * 2 + 0][n] = __builtin_amdgcn_mfma_f32_16x16x32_bf16(        \
          a01, Bf[n][1], acc[(q) * 2 + 0][n], 0, 0, 0);                     \
      acc[(q) * 2 + 1][n] = __builtin_amdgcn_mfma_f32_16x16x32_bf16(        \
          a10, Bf[n][0], acc[(q) * 2 + 1][n], 0, 0, 0);                     \
      acc[(q) * 2 + 1][n] = __builtin_amdgcn_mfma_f32_16x16x32_bf16(        \
          a11, Bf[n][1], acc[(q) * 2 + 1][n], 0, 0, 0);                     \
    }                                                                       \
    __builtin_amdgcn_s_setprio(0);                                          \
    EPI;                                                                    \
    {                                                                       \
      const int _vm = (VM);                                                 \
      if (_vm == 1) VMC_STEADY();                                           \
      else if (_vm == 2) asm volatile("s_waitcnt vmcnt(0)" ::: "memory");   \
    }                                                                       \
    __builtin_amdgcn_s_barrier();                                           \
    __builtin_amdgcn_sched_barrier(0);                                      \
  } while (0)

  const int nt = KK >> 6;        // K-tiles (even, >= 4)
  const int nit = nt >> 1;

  // prologue: buf0 <- tile0 (A+B), buf1.B <- tile1
  stA(0, 0, 0); stA(0, 1, 0); stB(0, 0, 0); stB(0, 1, 0);
  stB(1, 0, 1); stB(1, 1, 1);
  VMC_STEADY();
  __builtin_amdgcn_s_barrier();
  __builtin_amdgcn_sched_barrier(0);

#pragma unroll 1
  for (int it = 0; it < nit - 1; ++it) {
    const int t1 = 2 * it + 1, t2 = 2 * it + 2, t3 = 2 * it + 3;  // all < nt
    PHASE(0, 0, true,  { stA(1, 0, t1); }, 0, );            // ph1
    PHASE(0, 1, false, { stA(1, 1, t1); }, 0, );            // ph2
    PHASE(0, 2, false, { stB(0, 0, t2); }, 0, );            // ph3
    PHASE(0, 3, false, { stB(0, 1, t2); }, 1, );            // ph4
    PHASE(1, 0, true,  { stA(0, 0, t2); }, 0, );            // ph5
    PHASE(1, 1, false, { stA(0, 1, t2); }, 0, );            // ph6
    PHASE(1, 2, false, { stB(1, 0, t3); }, 0, );            // ph7
    PHASE(1, 3, false, { stB(1, 1, t3); }, 1, );            // ph8
  }
  {  // peeled final iteration: stores overlap ph5-8
    const int t1 = nt - 1;
    PHASE(0, 0, true,  { stA(1, 0, t1); }, 0, );
    PHASE(0, 1, false, { stA(1, 1, t1); }, 0, );
    PHASE(0, 2, false, { }, 0, );
    PHASE(0, 3, false, { }, 2, );                           // drain A1+B1
    PHASE(1, 0, true,  { }, 0, STOREQ(0));
    PHASE(1, 1, false, { }, 0, STOREQ(1));
    PHASE(1, 2, false, { }, 0, STOREQ(2));
    PHASE(1, 3, false, { }, 0, STOREQ(3));
  }
#undef PHASE
#undef STOREQ
#undef VMC_STEADY
}

extern "C" void kernel_launch(void* const* d_in, const int* in_sizes, int n_in,
                              void* d_out, int out_size, void* d_ws, size_t ws_size,
                              hipStream_t stream) {
  (void)in_sizes; (void)n_in; (void)out_size; (void)ws_size;
  const float* img = (const float*)d_in[0];   // [8192][1024] f32
  const float* W   = (const float*)d_in[1];   // [1024][2048] f32, cols unit-norm

  float* Rr = (float*)d_out;                   // r = alpha*(img@W), f32 [8192][2048]
  float* Pp = Rr + (size_t)NB * NK;            // pred = alpha*(img@Q), f32 [8192][1024]

  char* ws = (char*)d_ws;
  ushort_t* imgbf = (ushort_t*)(ws + 0);          // 16,777,216 B [8192][1024]
  ushort_t* Wt    = (ushort_t*)(ws + 16777216);   //  4,194,304 B [2048][1024]
  ushort_t* Wbf   = (ushort_t*)(ws + 20971520);   //  4,194,304 B [1024][2048]
  ushort_t* Qbf   = (ushort_t*)(ws + 25165824);   //  2,097,152 B [1024][1024]

  // W prep only: Wbf + Wt (512 blocks, ~16 MB traffic)
  prep_w_k<<<512, 256, 0, stream>>>(W, Wbf, Wt);

  // fused: Q = bf16(W@W^T) (blocks 0-255, MFMA/L2) + img->bf16 (256-1279, HBM)
  qimg_k<<<1280, 256, 0, stream>>>(Wbf, Qbf, img, imgbf);

  // r = alpha*(img @ W).  32x8 = 256 blocks, BN=256, K=1024 — one full round.
  gemm8ph<256><<<256, 512, 0, stream>>>(imgbf, Wt, NM, 8, NK, Rr);
  // pred = alpha*(img @ Q) (Q symmetric). 256 blocks, BN=128 — one full round.
  gemm8ph<128><<<256, 512, 0, stream>>>(imgbf, Qbf, NM, 8, NM, Pp);
}

// Round 14
// 92.525 us; speedup vs baseline: 1.9029x; 1.0961x over previous
//
#include <hip/hip_runtime.h>

// ---- problem constants ----
#define NB 8192      // batch rows
#define NM 1024      // image dim
#define NK 2048      // dictionary size

typedef unsigned short ushort_t;
using bf16x8 = __attribute__((ext_vector_type(8))) short;
using f32x4  = __attribute__((ext_vector_type(4))) float;

// T = 101 provably: accept at t=101 holds for all b/a > 0; flip at t=100
// would need b/a >= ~4e6 but b/a <= tr(W W^T) = 2048 (unit-norm cols).
__device__ __forceinline__ float alpha_const() {
  const double s = 0.1 * (2.0 / 8388608.0);
  return (float)(101.0 * s);
}

__device__ __forceinline__ ushort_t f2bf(float f) {
  union { float f; unsigned u; } v; v.f = f;
  unsigned r = (v.u + 0x7FFFu + ((v.u >> 16) & 1u)) >> 16;  // RNE
  return (ushort_t)r;
}

__device__ __forceinline__ void gload_lds16(const void* g, void* l) {
  __builtin_amdgcn_global_load_lds(
      (const __attribute__((address_space(1))) unsigned int*)g,
      (__attribute__((address_space(3))) unsigned int*)l, 16, 0, 0);
}

// ============ prep W: W->Wbf + tiled-transpose Wt (512 blocks) ===============
__global__ __launch_bounds__(256)
void prep_w_k(const float* __restrict__ W, ushort_t* __restrict__ Wbf,
              ushort_t* __restrict__ Wt)
{
  __shared__ ushort_t tile[64][65];
  const int tid = threadIdx.x;
  const int bW = blockIdx.x;                    // 512 tiles: 16(m) x 32(k)
  const int m0 = (bW >> 5) * 64, k0 = (bW & 31) * 64;
  const int r = tid >> 2, q = tid & 3;
  ushort_t loc[16];
#pragma unroll
  for (int j = 0; j < 4; ++j) {
    const float4 v = *(const float4*)&W[(size_t)(m0 + r) * NK + k0 + q * 16 + j * 4];
    loc[j * 4 + 0] = f2bf(v.x); loc[j * 4 + 1] = f2bf(v.y);
    loc[j * 4 + 2] = f2bf(v.z); loc[j * 4 + 3] = f2bf(v.w);
  }
#pragma unroll
  for (int j = 0; j < 4; ++j) {
    ushort4 o;
    o.x = loc[j * 4 + 0]; o.y = loc[j * 4 + 1];
    o.z = loc[j * 4 + 2]; o.w = loc[j * 4 + 3];
    *(ushort4*)&Wbf[(size_t)(m0 + r) * NK + k0 + q * 16 + j * 4] = o;
  }
#pragma unroll
  for (int jj = 0; jj < 16; ++jj) tile[r][q * 16 + jj] = loc[jj];
  __syncthreads();
  const int kk = tid >> 2, qq = tid & 3;
#pragma unroll
  for (int j = 0; j < 4; ++j) {
    ushort4 o;
    o.x = tile[qq * 16 + j * 4 + 0][kk];
    o.y = tile[qq * 16 + j * 4 + 1][kk];
    o.z = tile[qq * 16 + j * 4 + 2][kk];
    o.w = tile[qq * 16 + j * 4 + 3][kk];
    *(ushort4*)&Wt[(size_t)(k0 + kk) * NM + m0 + qq * 16 + j * 4] = o;
  }
}

// ==== fused: Q = bf16(W@W^T) on blocks 0-255 + img->bf16 on 256-1279 =========
__global__ __launch_bounds__(256)
void qimg_k(const ushort_t* __restrict__ Wbf, ushort_t* __restrict__ Qbf,
            const float* __restrict__ img, ushort_t* __restrict__ imgbf)
{
  __shared__ __align__(128) ushort_t As[64 * 64];
  __shared__ __align__(128) ushort_t Bs[64 * 64];
  const int tid = threadIdx.x;
  const int b = blockIdx.x;

  if (b >= 256) {
    const int base = (b - 256) * 2048;
#pragma unroll
    for (int i = 0; i < 8; ++i) {
      const int idx = base + i * 256 + tid;
      const float4 v = ((const float4*)img)[idx];
      ushort4 o;
      o.x = f2bf(v.x); o.y = f2bf(v.y); o.z = f2bf(v.z); o.w = f2bf(v.w);
      ((ushort4*)imgbf)[idx] = o;
    }
    return;
  }

  // ---- Q 64x64 tile: 4 waves as 2x2 of 32x32, K-step 64 ----
  const int w = tid >> 6, l = tid & 63;
  const int wm2 = w >> 1, wn2 = w & 1;
  const int bi = b >> 4, bj = b & 15;
  const int i0 = bi * 64, j0 = bj * 64;
  const int l15 = l & 15, l16 = l >> 4;
  const int lr = l >> 3;
  const int lc = (l & 7) * 8;

  f32x4 acc[2][2];
#pragma unroll
  for (int m = 0; m < 2; ++m)
#pragma unroll
    for (int n = 0; n < 2; ++n)
      acc[m][n] = (f32x4){0.f, 0.f, 0.f, 0.f};

  for (int k0 = 0; k0 < NK; k0 += 64) {
#pragma unroll
    for (int c = 0; c < 2; ++c) {
      const int rr = c * 32 + w * 8 + lr;
      const int base = c * 2048 + w * 512;
      gload_lds16(Wbf + (size_t)(i0 + rr) * NK + k0 + lc, &As[base]);
      gload_lds16(Wbf + (size_t)(j0 + rr) * NK + k0 + lc, &Bs[base]);
    }
    __syncthreads();
#pragma unroll
    for (int ks = 0; ks < 2; ++ks) {
      bf16x8 af[2], bfr[2];
#pragma unroll
      for (int m = 0; m < 2; ++m)
        af[m] = *(const bf16x8*)&As[(wm2 * 32 + m * 16 + l15) * 64 + ks * 32 + l16 * 8];
#pragma unroll
      for (int n = 0; n < 2; ++n)
        bfr[n] = *(const bf16x8*)&Bs[(wn2 * 32 + n * 16 + l15) * 64 + ks * 32 + l16 * 8];
#pragma unroll
      for (int m = 0; m < 2; ++m)
#pragma unroll
        for (int n = 0; n < 2; ++n)
          acc[m][n] = __builtin_amdgcn_mfma_f32_16x16x32_bf16(af[m], bfr[n], acc[m][n], 0, 0, 0);
    }
    __syncthreads();
  }

  // C/D layout: col = lane&15, row = (lane>>4)*4 + q
#pragma unroll
  for (int m = 0; m < 2; ++m)
#pragma unroll
    for (int n = 0; n < 2; ++n) {
      const int gr0 = i0 + wm2 * 32 + m * 16 + l16 * 4;
      const int gc  = j0 + wn2 * 32 + n * 16 + l15;
#pragma unroll
      for (int q = 0; q < 4; ++q)
        Qbf[(size_t)(gr0 + q) * NM + gc] = f2bf(acc[m][n][q]);
    }
}

// ============== 256xBN 8-phase deep-pipelined GEMM body ======================
// C = Aop * Bop^T, tile 256xBN, BK=64, 512 threads (8 waves, 2Mx4N).
// Steady iter (2 K-tiles): 8 phases {ds_read subtile | stage 1 half-tile |
// barrier | lgkmcnt(0) | setprio+16 MFMA | [vmcnt] | barrier}; counted vmcnt
// at ph4/ph8 only. Last iteration peeled: quadrant stores overlap ph5-8.
// XOR swizzle byte^=(row&7)<<4 : inverse-swizzled global src, swizzled ds_read.
// LDS carve: A = smem[0..65536), B = smem[65536 .. 65536+BN*64*2*2).
template<int BN>
__device__ __forceinline__
void gemm8ph_body(char* smem,
                  const ushort_t* __restrict__ Aop, const ushort_t* __restrict__ Bop,
                  int KK, int njb, int outld, float* __restrict__ outf,
                  int bid, int nblk)
{
  constexpr int WN  = BN / 4;    // wave N extent (64 or 32)
  constexpr int NFR = BN / 64;   // B frags per wave (4 or 2)

  const int tid = threadIdx.x;
  const int w = tid >> 6, l = tid & 63;
  const int wm = w >> 2, wn = w & 3;
  // XCD-aware swizzle within this half (nblk % 8 == 0)
  const int wg = (bid & 7) * (nblk >> 3) + (bid >> 3);
  const int bi = wg / njb, bj = wg % njb;
  const int i0 = bi * 256, j0 = bj * BN;
  const int l15 = l & 15, l16 = l >> 4;
  const int srow8 = l >> 3;          // lane row-in-8 for staging
  const int scb   = (l & 7) << 4;    // lane byte col for staging

  const float al = alpha_const();

  ushort_t* ldsA = (ushort_t*)smem;              // [2][256*64]
  ushort_t* ldsB = (ushort_t*)(smem + 65536);    // [2][BN*64]
  constexpr int ASTR = 256 * 64;                 // buf stride (elems)
  constexpr int BSTR = BN * 64;

  f32x4 acc[8][NFR];
#pragma unroll
  for (int m = 0; m < 8; ++m)
#pragma unroll
    for (int n = 0; n < NFR; ++n)
      acc[m][n] = (f32x4){0.f, 0.f, 0.f, 0.f};
  bf16x8 Bf[NFR][2];

  auto SH2 = [&](ushort_t* lb, const ushort_t* g0) {   // 128-row half
#pragma unroll
    for (int c = 0; c < 2; ++c) {
      const int row = (w * 2 + c) * 8 + srow8;
      const int sc = (scb ^ ((row & 7) << 4)) >> 1;
      gload_lds16(g0 + (size_t)row * (size_t)KK + sc, lb + (w * 2 + c) * 512);
    }
  };
  auto SH1 = [&](ushort_t* lb, const ushort_t* g0) {   // 64-row half
    const int row = w * 8 + srow8;
    const int sc = (scb ^ ((row & 7) << 4)) >> 1;
    gload_lds16(g0 + (size_t)row * (size_t)KK + sc, lb + w * 512);
  };
  auto stA = [&](int buf, int half, int kt) {
    SH2(ldsA + buf * ASTR + half * (128 * 64),
        Aop + (size_t)(i0 + half * 128) * (size_t)KK + (size_t)kt * 64);
  };
  auto stB = [&](int buf, int half, int kt) {
    if constexpr (BN == 256)
      SH2(ldsB + buf * BSTR + half * (128 * 64),
          Bop + (size_t)(j0 + half * 128) * (size_t)KK + (size_t)kt * 64);
    else
      SH1(ldsB + buf * BSTR + half * (64 * 64),
          Bop + (size_t)(j0 + half * 64) * (size_t)KK + (size_t)kt * 64);
  };
  auto rdA = [&](int buf, int R, int ks) -> bf16x8 {
    const int bc = ((ks * 64 + l16 * 16) ^ ((R & 7) << 4)) >> 1;
    return *(const bf16x8*)&ldsA[buf * ASTR + R * 64 + bc];
  };
  auto rdB = [&](int buf, int R, int ks) -> bf16x8 {
    const int bc = ((ks * 64 + l16 * 16) ^ ((R & 7) << 4)) >> 1;
    return *(const bf16x8*)&ldsB[buf * BSTR + R * 64 + bc];
  };

#define VMC_STEADY() do { \
    if constexpr (BN == 256) asm volatile("s_waitcnt vmcnt(4)" ::: "memory"); \
    else                     asm volatile("s_waitcnt vmcnt(2)" ::: "memory"); } while (0)

// store one C-quadrant (overlapped into peeled phases)
#define STOREQ(qd)                                                          \
  do {                                                                      \
    _Pragma("unroll")                                                       \
    for (int mm = 0; mm < 2; ++mm) {                                        \
      const int m = (qd) * 2 + mm;                                          \
      const int gr0 = i0 + wm * 128 + m * 16 + l16 * 4;                     \
      _Pragma("unroll")                                                     \
      for (int n = 0; n < NFR; ++n) {                                       \
        const int gc = j0 + wn * WN + n * 16 + l15;                         \
        _Pragma("unroll")                                                   \
        for (int qq = 0; qq < 4; ++qq) {                                    \
          const size_t idx = (size_t)(gr0 + qq) * (size_t)outld + gc;       \
          outf[idx] = al * acc[m][n][qq];                                   \
        }                                                                   \
      }                                                                     \
    }                                                                       \
  } while (0)

  // PHASE: LB=load Bf from bufc; STG=stage stmt; VM: 0 none 1 steady 2 drain;
  // EPI = post-MFMA statement (stores)
#define PHASE(bufc, q, LB, STG, VM, EPI)                                    \
  do {                                                                      \
    if (LB) {                                                               \
      _Pragma("unroll")                                                     \
      for (int n = 0; n < NFR; ++n) {                                       \
        Bf[n][0] = rdB(bufc, wn * WN + n * 16 + l15, 0);                    \
        Bf[n][1] = rdB(bufc, wn * WN + n * 16 + l15, 1);                    \
      }                                                                     \
    }                                                                       \
    bf16x8 a00 = rdA(bufc, wm * 128 + ((q) * 2 + 0) * 16 + l15, 0);         \
    bf16x8 a01 = rdA(bufc, wm * 128 + ((q) * 2 + 0) * 16 + l15, 1);         \
    bf16x8 a10 = rdA(bufc, wm * 128 + ((q) * 2 + 1) * 16 + l15, 0);         \
    bf16x8 a11 = rdA(bufc, wm * 128 + ((q) * 2 + 1) * 16 + l15, 1);         \
    STG;                                                                    \
    if (LB && BN == 256) asm volatile("s_waitcnt lgkmcnt(8)" ::: "memory"); \
    __builtin_amdgcn_s_barrier();                                           \
    asm volatile("s_waitcnt lgkmcnt(0)" ::: "memory");                      \
    __builtin_amdgcn_sched_barrier(0);                                      \
    __builtin_amdgcn_s_setprio(1);                                          \
    _Pragma("unroll")                                                       \
    for (int n = 0; n < NFR; ++n) {                                         \
      acc[(q) * 2 + 0][n] = __builtin_amdgcn_mfma_f32_16x16x32_bf16(        \
          a00, Bf[n][0], acc[(q) * 2 + 0][n], 0, 0, 0);                     \
      acc[(q) * 2 + 0][n] = __builtin_amdgcn_mfma_f32_16x16x32_bf16(        \
          a01, Bf[n][1], acc[(q) * 2 + 0][n], 0, 0, 0);                     \
      acc[(q) * 2 + 1][n] = __builtin_amdgcn_mfma_f32_16x16x32_bf16(        \
          a10, Bf[n][0], acc[(q) * 2 + 1][n], 0, 0, 0);                     \
      acc[(q) * 2 + 1][n] = __builtin_amdgcn_mfma_f32_16x16x32_bf16(        \
          a11, Bf[n][1], acc[(q) * 2 + 1][n], 0, 0, 0);                     \
    }                                                                       \
    __builtin_amdgcn_s_setprio(0);                                          \
    EPI;                                                                    \
    {                                                                       \
      const int _vm = (VM);                                                 \
      if (_vm == 1) VMC_STEADY();                                           \
      else if (_vm == 2) asm volatile("s_waitcnt vmcnt(0)" ::: "memory");   \
    }                                                                       \
    __builtin_amdgcn_s_barrier();                                           \
    __builtin_amdgcn_sched_barrier(0);                                      \
  } while (0)

  const int nt = KK >> 6;        // K-tiles (even, >= 4)
  const int nit = nt >> 1;

  // prologue: buf0 <- tile0 (A+B), buf1.B <- tile1
  stA(0, 0, 0); stA(0, 1, 0); stB(0, 0, 0); stB(0, 1, 0);
  stB(1, 0, 1); stB(1, 1, 1);
  VMC_STEADY();
  __builtin_amdgcn_s_barrier();
  __builtin_amdgcn_sched_barrier(0);

#pragma unroll 1
  for (int it = 0; it < nit - 1; ++it) {
    const int t1 = 2 * it + 1, t2 = 2 * it + 2, t3 = 2 * it + 3;  // all < nt
    PHASE(0, 0, true,  { stA(1, 0, t1); }, 0, );            // ph1
    PHASE(0, 1, false, { stA(1, 1, t1); }, 0, );            // ph2
    PHASE(0, 2, false, { stB(0, 0, t2); }, 0, );            // ph3
    PHASE(0, 3, false, { stB(0, 1, t2); }, 1, );            // ph4
    PHASE(1, 0, true,  { stA(0, 0, t2); }, 0, );            // ph5
    PHASE(1, 1, false, { stA(0, 1, t2); }, 0, );            // ph6
    PHASE(1, 2, false, { stB(1, 0, t3); }, 0, );            // ph7
    PHASE(1, 3, false, { stB(1, 1, t3); }, 1, );            // ph8
  }
  {  // peeled final iteration: stores overlap ph5-8
    const int t1 = nt - 1;
    PHASE(0, 0, true,  { stA(1, 0, t1); }, 0, );
    PHASE(0, 1, false, { stA(1, 1, t1); }, 0, );
    PHASE(0, 2, false, { }, 0, );
    PHASE(0, 3, false, { }, 2, );                           // drain A1+B1
    PHASE(1, 0, true,  { }, 0, STOREQ(0));
    PHASE(1, 1, false, { }, 0, STOREQ(1));
    PHASE(1, 2, false, { }, 0, STOREQ(2));
    PHASE(1, 3, false, { }, 0, STOREQ(3));
  }
#undef PHASE
#undef STOREQ
#undef VMC_STEADY
}

// fused finals: blocks 0-255 = r (BN=256), 256-511 = pred (BN=128).
// Exactly 2 full 256-block rounds at 1 block/CU; pred backfills r stragglers.
__global__ __launch_bounds__(512, 2)
void finals_k(const ushort_t* __restrict__ imgbf, const ushort_t* __restrict__ Wt,
              const ushort_t* __restrict__ Qbf,
              float* __restrict__ Rr, float* __restrict__ Pp)
{
  __shared__ __align__(1024) char smem[131072];
  const int b = blockIdx.x;
  if (b < 256)
    gemm8ph_body<256>(smem, imgbf, Wt, NM, 8, NK, Rr, b, 256);
  else
    gemm8ph_body<128>(smem, imgbf, Qbf, NM, 8, NM, Pp, b - 256, 256);
}

extern "C" void kernel_launch(void* const* d_in, const int* in_sizes, int n_in,
                              void* d_out, int out_size, void* d_ws, size_t ws_size,
                              hipStream_t stream) {
  (void)in_sizes; (void)n_in; (void)out_size; (void)ws_size;
  const float* img = (const float*)d_in[0];   // [8192][1024] f32
  const float* W   = (const float*)d_in[1];   // [1024][2048] f32, cols unit-norm

  float* Rr = (float*)d_out;                   // r = alpha*(img@W), f32 [8192][2048]
  float* Pp = Rr + (size_t)NB * NK;            // pred = alpha*(img@Q), f32 [8192][1024]

  char* ws = (char*)d_ws;
  ushort_t* imgbf = (ushort_t*)(ws + 0);          // 16,777,216 B [8192][1024]
  ushort_t* Wt    = (ushort_t*)(ws + 16777216);   //  4,194,304 B [2048][1024]
  ushort_t* Wbf   = (ushort_t*)(ws + 20971520);   //  4,194,304 B [1024][2048]
  ushort_t* Qbf   = (ushort_t*)(ws + 25165824);   //  2,097,152 B [1024][1024]

  // W prep only: Wbf + Wt (512 blocks, ~16 MB traffic)
  prep_w_k<<<512, 256, 0, stream>>>(W, Wbf, Wt);

  // fused: Q = bf16(W@W^T) (blocks 0-255, MFMA/L2) + img->bf16 (256-1279, HBM)
  qimg_k<<<1280, 256, 0, stream>>>(Wbf, Qbf, img, imgbf);

  // fused finals: r (blocks 0-255) + pred (256-511), 2 exact rounds.
  finals_k<<<512, 512, 0, stream>>>(imgbf, Wt, Qbf, Rr, Pp);
}